// Round 1
// baseline (1126.152 us; speedup 1.0000x reference)
//
#include <hip/hip_runtime.h>

// SeparableGateS2Activation + SwiGLU merge, fp32 baseline.
// out[n,k,c] = sigmoid(s[n,256+c]) * sum_pq F[pq,k] * (T@X1)[pq,c]*(T@X2)[pq,c]
//              + (k==0 ? silu(s[n,c])*s[n,128+c] : 0)

#define KC   49     // NUM_COEF
#define CC   128    // C
#define CC2  256    // 2C
#define PQ   324    // RES*RES
#define PQT  32     // pq tile
#define NTI  11     // ceil(PQ/PQT) -> padded to 352
#define FPAD 52     // row pad for T/F tiles (16B-aligned rows)

__global__ __launch_bounds__(256, 2)
void fused_s2_kernel(const float* __restrict__ inputs,   // [N][49][256]
                     const float* __restrict__ scalars,  // [N][384]
                     const float* __restrict__ Tg,       // [324][49]
                     const float* __restrict__ Fg,       // [324][49]
                     float* __restrict__ out)            // [N][49][128]
{
    __shared__ __align__(16) float Xs[KC][CC2];      // 50176 B
    __shared__ __align__(16) float Trow[PQT][FPAD];  //  6656 B
    __shared__ __align__(16) float Ftile[PQT][FPAD]; //  6656 B
    __shared__ __align__(16) float Gt[PQT][CC];      // 16384 B  -> 79872 B total

    const int n = blockIdx.x;
    const int t = threadIdx.x;
    const int c = t & (CC - 1);
    const int h = t >> 7;   // wave-uniform (threads 0-127 vs 128-255)

    // ---- stage X_n into LDS (float4, coalesced) ----
    {
        const float4* src = (const float4*)(inputs + (size_t)n * (KC * CC2));
        float4* dst = (float4*)(&Xs[0][0]);
        for (int idx = t; idx < (KC * CC2) / 4; idx += 256) dst[idx] = src[idx];
    }

    // ---- scalar path ----
    const float* sp = scalars + (size_t)n * (3 * CC);
    const float sa = sp[c];
    const float sb = sp[CC + c];
    const float sg = sp[2 * CC + c];
    const float gate = 1.0f / (1.0f + expf(-sg));          // sigmoid
    const float osc  = (sa / (1.0f + expf(-sa))) * sb;     // silu(a)*b

    float acc[25];
#pragma unroll
    for (int i = 0; i < 25; ++i) acc[i] = 0.0f;

    for (int tile = 0; tile < NTI; ++tile) {
        const int pqbase = tile * PQT;
        __syncthreads();  // prev-tile phase-2 reads done (covers Xs load on tile 0)

        // ---- stage T/F tiles (coalesced global, clean LDS writes, zero-pad) ----
        for (int idx = t; idx < 2 * PQT * KC; idx += 256) {
            const int m   = idx / (PQT * KC);
            const int r   = idx - m * (PQT * KC);
            const int pql = r / KC;
            const int k   = r - pql * KC;
            const int pq  = pqbase + pql;
            float v = 0.0f;
            if (pq < PQ) v = m ? Fg[pq * KC + k] : Tg[pq * KC + k];
            if (m) Ftile[pql][k] = v; else Trow[pql][k] = v;
        }
        __syncthreads();

        // ---- phase 1: g[pq,c] = (T@X1)*(T@X2), 16 pq rows per thread ----
        float s1[16], s2[16];
#pragma unroll
        for (int j = 0; j < 16; ++j) { s1[j] = 0.0f; s2[j] = 0.0f; }

        for (int i4 = 0; i4 < 12; ++i4) {
            const int i0 = i4 * 4;
            float x1[4], x2[4];
#pragma unroll
            for (int u = 0; u < 4; ++u) {
                x1[u] = Xs[i0 + u][c];
                x2[u] = Xs[i0 + u][c + CC];
            }
#pragma unroll
            for (int j = 0; j < 16; ++j) {
                const float4 tv = *(const float4*)(&Trow[h * 16 + j][i0]); // broadcast
                s1[j] = fmaf(tv.x, x1[0], s1[j]);
                s1[j] = fmaf(tv.y, x1[1], s1[j]);
                s1[j] = fmaf(tv.z, x1[2], s1[j]);
                s1[j] = fmaf(tv.w, x1[3], s1[j]);
                s2[j] = fmaf(tv.x, x2[0], s2[j]);
                s2[j] = fmaf(tv.y, x2[1], s2[j]);
                s2[j] = fmaf(tv.z, x2[2], s2[j]);
                s2[j] = fmaf(tv.w, x2[3], s2[j]);
            }
        }
        {   // tail i = 48
            const float x1 = Xs[48][c];
            const float x2 = Xs[48][c + CC];
#pragma unroll
            for (int j = 0; j < 16; ++j) {
                const float tv = Trow[h * 16 + j][48];
                s1[j] = fmaf(tv, x1, s1[j]);
                s2[j] = fmaf(tv, x2, s2[j]);
            }
        }
#pragma unroll
        for (int j = 0; j < 16; ++j) Gt[h * 16 + j][c] = s1[j] * s2[j];
        __syncthreads();

        // ---- phase 2: acc[k] += F[pq,k] * g[pq,c]; h=0 -> k 0..23, h=1 -> k 24..48
        for (int pql = 0; pql < PQT; ++pql) {
            const float gv = Gt[pql][c];
            const float4* fp = (const float4*)(&Ftile[pql][h * 24]);
#pragma unroll
            for (int q6 = 0; q6 < 6; ++q6) {
                const float4 f = fp[q6];
                acc[q6 * 4 + 0] = fmaf(f.x, gv, acc[q6 * 4 + 0]);
                acc[q6 * 4 + 1] = fmaf(f.y, gv, acc[q6 * 4 + 1]);
                acc[q6 * 4 + 2] = fmaf(f.z, gv, acc[q6 * 4 + 2]);
                acc[q6 * 4 + 3] = fmaf(f.w, gv, acc[q6 * 4 + 3]);
            }
            if (h) acc[24] = fmaf(Ftile[pql][48], gv, acc[24]);
        }
    }

    // ---- epilogue: gate, SwiGLU merge at k==0, write ----
    const int kcnt = 24 + h;           // h=0: k 0..23, h=1: k 24..48
    float* op = out + ((size_t)n * KC + (size_t)(h * 24)) * CC + c;
    for (int kk = 0; kk < kcnt; ++kk) {
        float v = gate * acc[kk];
        if (h == 0 && kk == 0) v += osc;
        op[(size_t)kk * CC] = v;
    }
}

extern "C" void kernel_launch(void* const* d_in, const int* in_sizes, int n_in,
                              void* d_out, int out_size, void* d_ws, size_t ws_size,
                              hipStream_t stream) {
    const float* inputs  = (const float*)d_in[0];
    const float* scalars = (const float*)d_in[1];
    const float* Tg      = (const float*)d_in[2];
    const float* Fg      = (const float*)d_in[3];
    float* outp          = (float*)d_out;

    const int N = in_sizes[1] / (3 * CC);   // scalars is [N][384]
    hipLaunchKernelGGL(fused_s2_kernel, dim3(N), dim3(256), 0, stream,
                       inputs, scalars, Tg, Fg, outp);
}

// Round 2
// 225.730 us; speedup vs baseline: 4.9889x; 4.9889x over previous
//
#include <hip/hip_runtime.h>

// bf16-MFMA rewrite.
// out[n,k,c] = sigmoid(s[n,256+c]) * sum_pq F[pq,k]*(T@X1)[pq,c]*(T@X2)[pq,c]
//              + (k==0 ? silu(s[n,c])*s[n,128+c] : 0)

#define KC   49
#define PQ   324
#define NPX  12544      // 49*256
#define GROW 200        // gT row length (elems): 192 used + 8 pad

typedef __attribute__((ext_vector_type(8))) short bf16x8;
typedef __attribute__((ext_vector_type(4))) short bf16x4;
typedef __attribute__((ext_vector_type(4))) float f32x4;

__device__ __forceinline__ unsigned short f2bf(float f) {
    unsigned u = __builtin_bit_cast(unsigned, f);
    return (unsigned short)((u + 0x7FFFu + ((u >> 16) & 1u)) >> 16);   // RNE
}

// ---- precompute: Tw[336][64] = pad(T[pq][i]) bf16 ; Fw[64][384] = pad(F^T[k][pq]) bf16
__global__ void prep_kernel(const float* __restrict__ Tg, const float* __restrict__ Fg,
                            unsigned short* __restrict__ Tw, unsigned short* __restrict__ Fw)
{
    int idx = blockIdx.x * 256 + threadIdx.x;
    if (idx < 336 * 64) {
        int pq = idx >> 6, i = idx & 63;
        float v = (pq < PQ && i < KC) ? Tg[pq * KC + i] : 0.0f;
        Tw[idx] = f2bf(v);
    }
    int idx2 = idx - 336 * 64;
    if (idx2 >= 0 && idx2 < 64 * 384) {
        int k = idx2 / 384, pq = idx2 - k * 384;
        float v = (k < KC && pq < PQ) ? Fg[pq * KC + k] : 0.0f;
        Fw[idx2] = f2bf(v);
    }
}

__global__ __launch_bounds__(64, 3)
void s2_mfma_kernel(const float* __restrict__ X,            // [N][49][256]
                    const float* __restrict__ S,            // [N][384]
                    const unsigned short* __restrict__ Tw,  // [336][64]
                    const unsigned short* __restrict__ Fw,  // [64][384]
                    float* __restrict__ out,                // [N][49][128]
                    int cpx)                                // grid/8 (0 = no swizzle)
{
    __shared__ __align__(16) unsigned short gT[32][GROW];   // wave-private c-major g

    const int b  = blockIdx.x;
    const int l  = cpx ? ((b & 7) * cpx + (b >> 3)) : b;    // XCD-bijective swizzle
    const int n  = l >> 2;
    const int w  = l & 3;                                   // c-slice: 32w..32w+31
    const int t  = threadIdx.x;
    const int lo = t & 15;
    const int hi = t >> 4;

    // ---- scalar path (issue early) ----
    const float* sp = S + (size_t)n * 384;
    float sg[2], osc[2];
#pragma unroll
    for (int nt = 0; nt < 2; ++nt) {
        const int c = 32 * w + 16 * nt + lo;
        const float g = sp[256 + c];
        const float a = sp[c];
        const float bb = sp[128 + c];
        sg[nt]  = 1.0f / (1.0f + expf(-g));
        osc[nt] = (a / (1.0f + expf(-a))) * bb;
    }

    // ---- gather X B-frags (each element read once chip-wide), hold in regs ----
    bf16x8 bx[2][2][2];   // [xi][ntl][ks]
    {
        const float* xn = X + (size_t)n * NPX;
#pragma unroll
        for (int xi = 0; xi < 2; ++xi)
#pragma unroll
        for (int ntl = 0; ntl < 2; ++ntl) {
            const float* cp = xn + (32 * w + 16 * ntl + lo + 128 * xi);
#pragma unroll
            for (int ks = 0; ks < 2; ++ks) {
                bf16x8 v;
#pragma unroll
                for (int j = 0; j < 8; ++j) {
                    const int i = 32 * ks + 8 * hi + j;
                    const float f = (i < KC) ? cp[i * 256] : 0.0f;
                    v[j] = (short)f2bf(f);
                }
                bx[xi][ntl][ks] = v;
            }
        }
    }

    f32x4 accO[4][2];
#pragma unroll
    for (int m = 0; m < 4; ++m)
#pragma unroll
    for (int nt = 0; nt < 2; ++nt) accO[m][nt] = (f32x4){0.f, 0.f, 0.f, 0.f};

    for (int hf = 0; hf < 2; ++hf) {
        // zero gT elems [160,192) of each row (pq tail; also covers half-2 stale rows)
        {
            const f32x4 z = {0.f, 0.f, 0.f, 0.f};
            char* row = (char*)&gT[t >> 1][0];
            *(f32x4*)(row + 320 + 16 * (t & 1)) = z;
            *(f32x4*)(row + 352 + 16 * (t & 1)) = z;
        }

        const int nmt = hf ? 10 : 11;
        // ---- GEMM1 + gating: g[pq_local, c_rel] into gT ----
        const unsigned short* trow = Tw + (size_t)lo * 64 + 8 * hi + (size_t)(11 * 16 * 64) * hf;
        bf16x8 a0 = *(const bf16x8*)(trow);
        bf16x8 a1 = *(const bf16x8*)(trow + 32);
        for (int mtl = 0; mtl < nmt; ++mtl) {
            const int nx = (mtl + 1 < nmt) ? mtl + 1 : mtl;
            const unsigned short* tn = trow + (size_t)nx * 1024;   // 16 rows * 64
            bf16x8 na0 = *(const bf16x8*)(tn);
            bf16x8 na1 = *(const bf16x8*)(tn + 32);

            f32x4 ac[2][2];
#pragma unroll
            for (int xi = 0; xi < 2; ++xi)
#pragma unroll
            for (int ntl = 0; ntl < 2; ++ntl) {
                f32x4 a = (f32x4){0.f, 0.f, 0.f, 0.f};
                a = __builtin_amdgcn_mfma_f32_16x16x32_bf16(a0, bx[xi][ntl][0], a, 0, 0, 0);
                a = __builtin_amdgcn_mfma_f32_16x16x32_bf16(a1, bx[xi][ntl][1], a, 0, 0, 0);
                ac[xi][ntl] = a;
            }
#pragma unroll
            for (int ntl = 0; ntl < 2; ++ntl) {
                bf16x4 gv;
#pragma unroll
                for (int r = 0; r < 4; ++r)
                    gv[r] = (short)f2bf(ac[0][ntl][r] * ac[1][ntl][r]);
                *(bf16x4*)&gT[16 * ntl + lo][16 * mtl + 4 * hi] = gv;
            }
            a0 = na0; a1 = na1;
        }

        // ---- GEMM2: accO[k_tile][ntl2] += F^T-frag x g-frag over 6 K32 steps ----
        const unsigned short* frow = Fw + (size_t)lo * 384 + 176 * hf + 8 * hi;
        bf16x8 af[4];
#pragma unroll
        for (int m = 0; m < 4; ++m) af[m] = *(const bf16x8*)(frow + (size_t)m * 6144);
        for (int ks = 0; ks < 6; ++ks) {
            const int kn = (ks < 5) ? ks + 1 : ks;
            bf16x8 afn[4];
#pragma unroll
            for (int m = 0; m < 4; ++m)
                afn[m] = *(const bf16x8*)(frow + (size_t)m * 6144 + kn * 32);

            const bf16x8 bg0 = *(const bf16x8*)&gT[lo][32 * ks + 8 * hi];
            const bf16x8 bg1 = *(const bf16x8*)&gT[16 + lo][32 * ks + 8 * hi];
#pragma unroll
            for (int m = 0; m < 4; ++m) {
                accO[m][0] = __builtin_amdgcn_mfma_f32_16x16x32_bf16(af[m], bg0, accO[m][0], 0, 0, 0);
                accO[m][1] = __builtin_amdgcn_mfma_f32_16x16x32_bf16(af[m], bg1, accO[m][1], 0, 0, 0);
            }
#pragma unroll
            for (int m = 0; m < 4; ++m) af[m] = afn[m];
        }
    }

    // ---- epilogue: gate, merge, store ----
    float* op = out + (size_t)n * (KC * 128) + 32 * w + lo;
#pragma unroll
    for (int m = 0; m < 4; ++m)
#pragma unroll
    for (int nt = 0; nt < 2; ++nt)
#pragma unroll
    for (int r = 0; r < 4; ++r) {
        const int k = 16 * m + 4 * hi + r;
        if (k < KC) {
            float v = sg[nt] * accO[m][nt][r];
            if (k == 0) v += osc[nt];
            op[(size_t)k * 128 + 16 * nt] = v;
        }
    }
}

extern "C" void kernel_launch(void* const* d_in, const int* in_sizes, int n_in,
                              void* d_out, int out_size, void* d_ws, size_t ws_size,
                              hipStream_t stream) {
    const float* inputs  = (const float*)d_in[0];
    const float* scalars = (const float*)d_in[1];
    const float* Tg      = (const float*)d_in[2];
    const float* Fg      = (const float*)d_in[3];
    float* outp          = (float*)d_out;

    unsigned short* Tw = (unsigned short*)d_ws;          // 336*64  = 21504 elems
    unsigned short* Fw = Tw + 336 * 64;                  // 64*384  = 24576 elems (92160 B total)

    const int N = in_sizes[1] / 384;
    hipLaunchKernelGGL(prep_kernel, dim3(180), dim3(256), 0, stream, Tg, Fg, Tw, Fw);

    const int nwg = 4 * N;
    const int cpx = ((nwg & 7) == 0) ? (nwg >> 3) : 0;
    hipLaunchKernelGGL(s2_mfma_kernel, dim3(nwg), dim3(64), 0, stream,
                       inputs, scalars, Tw, Fw, outp, cpx);
}

// Round 3
// 217.900 us; speedup vs baseline: 5.1682x; 1.0359x over previous
//
#include <hip/hip_runtime.h>

// 32x32x16-MFMA, zero-LDS fused kernel.
// out[n,k,c] = sigmoid(s[n,256+c]) * sum_pq F[pq,k]*(T@X1)[pq,c]*(T@X2)[pq,c]
//              + (k==0 ? silu(s[n,c])*s[n,128+c] : 0)

#define KC   49
#define PQ   324
#define NPX  12544      // 49*256
#define OUTK 6272       // 49*128

typedef __attribute__((ext_vector_type(8)))  short bf16x8;
typedef __attribute__((ext_vector_type(16))) float f32x16;
typedef __attribute__((ext_vector_type(4)))  unsigned int u32x4;

__device__ __forceinline__ unsigned int cvtpk_bf16(float lo, float hi) {
    unsigned int r;
    asm("v_cvt_pk_bf16_f32 %0, %1, %2" : "=v"(r) : "v"(lo), "v"(hi));
    return r;
}

__device__ __forceinline__ unsigned short f2bf(float f) {
    unsigned u = __builtin_bit_cast(unsigned, f);
    return (unsigned short)((u + 0x7FFFu + ((u >> 16) & 1u)) >> 16);   // RNE
}

// Tw[352][64] = pad(T[pq][i]) bf16 ; Fw[64][384] = pad(F^T[k][pq]) bf16
__global__ void prep_kernel(const float* __restrict__ Tg, const float* __restrict__ Fg,
                            unsigned short* __restrict__ Tw, unsigned short* __restrict__ Fw)
{
    int idx = blockIdx.x * 256 + threadIdx.x;
    if (idx < 352 * 64) {
        int pq = idx >> 6, i = idx & 63;
        float v = (pq < PQ && i < KC) ? Tg[pq * KC + i] : 0.0f;
        Tw[idx] = f2bf(v);
    }
    int idx2 = idx - 352 * 64;
    if (idx2 >= 0 && idx2 < 64 * 384) {
        int k = idx2 / 384, pq = idx2 - k * 384;
        float v = (k < KC && pq < PQ) ? Fg[pq * KC + k] : 0.0f;
        Fw[idx2] = f2bf(v);
    }
}

__global__ __launch_bounds__(256, 3)
void s2_mfma32(const float* __restrict__ X,            // [N][49][256]
               const float* __restrict__ S,            // [N][384]
               const unsigned short* __restrict__ Tw,  // [352][64]
               const unsigned short* __restrict__ Fw,  // [64][384]
               float* __restrict__ out)                // [N][49][128]
{
    const int n  = blockIdx.x;
    const int w  = threadIdx.x >> 6;    // c-slice 32w..32w+31
    const int l  = threadIdx.x & 63;
    const int cl = l & 31;
    const int hb = l >> 5;

    // ---- scalar path ----
    const float* sp = S + (size_t)n * 384 + 32 * w + cl;
    const float sa = sp[0], sb = sp[128], sgv = sp[256];
    const float sg  = 1.0f / (1.0f + __expf(-sgv));
    const float osc = (sa / (1.0f + __expf(-sa))) * sb;

    // ---- X B-frags: lane (c=cl, hb) elem j = X[i=16st+8hb+j][c], held whole kernel ----
    bf16x8 bx[2][4];
    {
        const float* xp = X + (size_t)n * NPX + 32 * w + cl;
#pragma unroll
        for (int xi = 0; xi < 2; ++xi)
#pragma unroll
        for (int st = 0; st < 4; ++st) {
            float f[8];
#pragma unroll
            for (int j = 0; j < 8; ++j) {
                const int i = 16 * st + 8 * hb + j;
                f[j] = (i < KC) ? xp[128 * xi + (size_t)i * 256] : 0.0f;
            }
            u32x4 d;
#pragma unroll
            for (int p = 0; p < 4; ++p) d[p] = cvtpk_bf16(f[2 * p], f[2 * p + 1]);
            bx[xi][st] = __builtin_bit_cast(bf16x8, d);
        }
    }

    f32x16 accO0, accO1, fz;
#pragma unroll
    for (int r = 0; r < 16; ++r) { accO0[r] = 0.0f; accO1[r] = 0.0f; fz[r] = 0.0f; }

    const unsigned short* twp = Tw + (size_t)cl * 64 + 8 * hb;    // += 2048/tile
    const unsigned short* fw0 = Fw + (size_t)cl * 384 + 8 * hb;   // k-tile 0
    const unsigned short* fw1 = fw0 + (size_t)32 * 384;           // k-tile 1

    for (int t = 0; t < 11; ++t) {
        // A-frags for this tile (L2-resident constants)
        const bf16x8 ta0 = *(const bf16x8*)(twp);
        const bf16x8 ta1 = *(const bf16x8*)(twp + 16);
        const bf16x8 ta2 = *(const bf16x8*)(twp + 32);
        const bf16x8 ta3 = *(const bf16x8*)(twp + 48);
        const int col = 32 * t;
        const bf16x8 fa00 = *(const bf16x8*)(fw0 + col);
        const bf16x8 fa01 = *(const bf16x8*)(fw0 + col + 16);
        const bf16x8 fa10 = *(const bf16x8*)(fw1 + col);
        const bf16x8 fa11 = *(const bf16x8*)(fw1 + col + 16);

        // GEMM1: 32pq x 32c, K=64 in 4 steps, both halves x1/x2
        f32x16 ac0 = fz, ac1 = fz;
        ac0 = __builtin_amdgcn_mfma_f32_32x32x16_bf16(ta0, bx[0][0], ac0, 0, 0, 0);
        ac1 = __builtin_amdgcn_mfma_f32_32x32x16_bf16(ta0, bx[1][0], ac1, 0, 0, 0);
        ac0 = __builtin_amdgcn_mfma_f32_32x32x16_bf16(ta1, bx[0][1], ac0, 0, 0, 0);
        ac1 = __builtin_amdgcn_mfma_f32_32x32x16_bf16(ta1, bx[1][1], ac1, 0, 0, 0);
        ac0 = __builtin_amdgcn_mfma_f32_32x32x16_bf16(ta2, bx[0][2], ac0, 0, 0, 0);
        ac1 = __builtin_amdgcn_mfma_f32_32x32x16_bf16(ta2, bx[1][2], ac1, 0, 0, 0);
        ac0 = __builtin_amdgcn_mfma_f32_32x32x16_bf16(ta3, bx[0][3], ac0, 0, 0, 0);
        ac1 = __builtin_amdgcn_mfma_f32_32x32x16_bf16(ta3, bx[1][3], ac1, 0, 0, 0);

        // gate + pack: q[p] = bf16pair(g[R(2p)], g[R(2p+1)]), R(r)=(r&3)+8(r>>2)+4hb
        unsigned int q0 = cvtpk_bf16(ac0[0]  * ac1[0],  ac0[1]  * ac1[1]);
        unsigned int q1 = cvtpk_bf16(ac0[2]  * ac1[2],  ac0[3]  * ac1[3]);
        unsigned int q2 = cvtpk_bf16(ac0[4]  * ac1[4],  ac0[5]  * ac1[5]);
        unsigned int q3 = cvtpk_bf16(ac0[6]  * ac1[6],  ac0[7]  * ac1[7]);
        unsigned int q4 = cvtpk_bf16(ac0[8]  * ac1[8],  ac0[9]  * ac1[9]);
        unsigned int q5 = cvtpk_bf16(ac0[10] * ac1[10], ac0[11] * ac1[11]);
        unsigned int q6 = cvtpk_bf16(ac0[12] * ac1[12], ac0[13] * ac1[13]);
        unsigned int q7 = cvtpk_bf16(ac0[14] * ac1[14], ac0[15] * ac1[15]);

        // half-wave exchange: C-layout (4-row groups) -> B-frag layout (8-row groups)
        asm("v_permlane32_swap_b32 %0, %1" : "+v"(q0), "+v"(q2));
        asm("v_permlane32_swap_b32 %0, %1" : "+v"(q1), "+v"(q3));
        asm("v_permlane32_swap_b32 %0, %1" : "+v"(q4), "+v"(q6));
        asm("v_permlane32_swap_b32 %0, %1" : "+v"(q5), "+v"(q7));
        u32x4 b0v, b1v;
        b0v[0] = q0; b0v[1] = q1; b0v[2] = q2; b0v[3] = q3;
        b1v[0] = q4; b1v[1] = q5; b1v[2] = q6; b1v[3] = q7;
        const bf16x8 bg0 = __builtin_bit_cast(bf16x8, b0v);
        const bf16x8 bg1 = __builtin_bit_cast(bf16x8, b1v);

        // GEMM2: out-tiles k 0..31 and 32..63, two K=16 pq-steps
        accO0 = __builtin_amdgcn_mfma_f32_32x32x16_bf16(fa00, bg0, accO0, 0, 0, 0);
        accO1 = __builtin_amdgcn_mfma_f32_32x32x16_bf16(fa10, bg0, accO1, 0, 0, 0);
        accO0 = __builtin_amdgcn_mfma_f32_32x32x16_bf16(fa01, bg1, accO0, 0, 0, 0);
        accO1 = __builtin_amdgcn_mfma_f32_32x32x16_bf16(fa11, bg1, accO1, 0, 0, 0);

        twp += 2048;
    }

    // ---- epilogue: gate, SwiGLU merge at k==0, store ----
    float* op = out + (size_t)n * OUTK + 32 * w + cl;
#pragma unroll
    for (int r = 0; r < 16; ++r) {
        const int k0 = (r & 3) + 8 * (r >> 2) + 4 * hb;
        float v = sg * accO0[r];
        if (k0 == 0) v += osc;               // only r==0, hb==0
        op[(size_t)k0 * 128] = v;
        const int k1 = 32 + k0;
        if (k1 < KC) op[(size_t)k1 * 128] = sg * accO1[r];
    }
}

extern "C" void kernel_launch(void* const* d_in, const int* in_sizes, int n_in,
                              void* d_out, int out_size, void* d_ws, size_t ws_size,
                              hipStream_t stream) {
    const float* inputs  = (const float*)d_in[0];
    const float* scalars = (const float*)d_in[1];
    const float* Tg      = (const float*)d_in[2];
    const float* Fg      = (const float*)d_in[3];
    float* outp          = (float*)d_out;

    unsigned short* Tw = (unsigned short*)d_ws;      // 352*64 = 22528 elems
    unsigned short* Fw = Tw + 352 * 64;              // 64*384 = 24576 elems (94208 B total)

    const int N = in_sizes[1] / 384;
    hipLaunchKernelGGL(prep_kernel, dim3(184), dim3(256), 0, stream, Tg, Fg, Tw, Fw);
    hipLaunchKernelGGL(s2_mfma32, dim3(N), dim3(256), 0, stream,
                       inputs, scalars, Tw, Fw, outp);
}

// Round 4
// 94.765 us; speedup vs baseline: 11.8836x; 2.2994x over previous
//
#include <hip/hip_runtime.h>

// Block-resident-LDS fused kernel.
// out[n,k,c] = sigmoid(s[n,256+c]) * sum_pq F[pq,k]*(T@X1)[pq,c]*(T@X2)[pq,c]
//              + (k==0 ? silu(s[n,c])*s[n,128+c] : 0)

#define KC    49
#define PQ    324
#define NPX   12544     // 49*256
#define OUTK  6272      // 49*128
#define NTILE 11
// tiled+padded weights in d_ws, staged whole into LDS per block:
// Tw: [11 tiles][32 pq][72 i]  bf16 (144 B rows, 4-way-conflict-free-ish b128 reads)
// Fw: [11 tiles][64 k ][40 pq] bf16 (80 B rows)
#define TWROW  72
#define TWTILE 2304     // 32*72
#define TWTOT  25344    // 11*TWTILE
#define FWROW  40
#define FWTILE 2560     // 64*40
#define FWTOT  28160    // 11*FWTILE
#define WTOT   (TWTOT + FWTOT)   // 53504 elems = 107008 B

typedef __attribute__((ext_vector_type(8)))  short bf16x8;
typedef __attribute__((ext_vector_type(16))) float f32x16;
typedef __attribute__((ext_vector_type(4)))  unsigned int u32x4;

__device__ __forceinline__ unsigned int cvtpk_bf16(float lo, float hi) {
    unsigned int r;
    asm("v_cvt_pk_bf16_f32 %0, %1, %2" : "=v"(r) : "v"(lo), "v"(hi));
    return r;
}
__device__ __forceinline__ unsigned short f2bf(float f) {
    unsigned u = __builtin_bit_cast(unsigned, f);
    return (unsigned short)((u + 0x7FFFu + ((u >> 16) & 1u)) >> 16);   // RNE
}

__global__ void prep_kernel(const float* __restrict__ Tg, const float* __restrict__ Fg,
                            unsigned short* __restrict__ W)
{
    const int idx = blockIdx.x * 256 + threadIdx.x;
    if (idx < TWTOT) {
        const int t = idx / TWTILE, rem = idx % TWTILE;
        const int r = rem / TWROW,  i   = rem % TWROW;
        const int pq = 32 * t + r;
        const float v = (i < KC && pq < PQ) ? Tg[pq * KC + i] : 0.0f;
        W[idx] = f2bf(v);
    } else if (idx < WTOT) {
        const int idx2 = idx - TWTOT;
        const int t = idx2 / FWTILE, rem = idx2 % FWTILE;
        const int k = rem / FWROW,   p   = rem % FWROW;
        const int pq = 32 * t + p;
        const float v = (k < KC && p < 32 && pq < PQ) ? Fg[pq * KC + k] : 0.0f;
        W[idx] = f2bf(v);
    }
}

__global__ __launch_bounds__(512, 2)
void s2_fused(const float* __restrict__ X,            // [N][49][256]
              const float* __restrict__ S,            // [N][384]
              const unsigned short* __restrict__ W,   // tiled Tw+Fw blob
              float* __restrict__ out,                // [N][49][128]
              int nit)                                // n-pairs per block
{
    __shared__ __align__(16) unsigned short lds[WTOT];   // 107008 B -> 1 block/CU

    const int tid = threadIdx.x;
    // ---- one-time stage of tiled T/F into LDS (16 B per thread per round) ----
    for (int idx = tid; idx < WTOT / 8; idx += 512) {
        const u32x4 v = *(const u32x4*)(W + (size_t)idx * 8);
        *(u32x4*)(lds + (size_t)idx * 8) = v;
    }
    __syncthreads();   // only barrier in the kernel; LDS is read-only afterwards

    const int w  = tid >> 6;
    const int l  = tid & 63;
    const int cl = l & 31;
    const int hb = l >> 5;
    const int cs = w >> 1;   // c-slice 0..3 (c = 32*cs + cl)
    const int nw = w & 1;    // which n of the pair

    const unsigned short* tw = lds;
    const unsigned short* fw = lds + TWTOT;

    const int nbase = blockIdx.x * (2 * nit) + nw;

    float fr[2][4][8];             // raw fp32 X gather (next-n pipeline)
    float sraw0, sraw1, sraw2;

    // ---- prologue gather for first n ----
    {
        const float* xp = X + (size_t)nbase * NPX + 32 * cs + cl;
#pragma unroll
        for (int xi = 0; xi < 2; ++xi)
#pragma unroll
        for (int st = 0; st < 4; ++st)
#pragma unroll
        for (int j = 0; j < 8; ++j) {
            const int i = 16 * st + 8 * hb + j;
            fr[xi][st][j] = (i < KC) ? xp[128 * xi + (size_t)i * 256] : 0.0f;
        }
        const float* sp = S + (size_t)nbase * 384 + 32 * cs + cl;
        sraw0 = sp[0]; sraw1 = sp[128]; sraw2 = sp[256];
    }

    for (int it = 0; it < nit; ++it) {
        const int n = nbase + 2 * it;

        // activations for current n (before sraw is overwritten)
        const float sg  = 1.0f / (1.0f + __expf(-sraw2));
        const float osc = (sraw0 / (1.0f + __expf(-sraw0))) * sraw1;

        // convert current gather to bf16 B-frags
        bf16x8 bx[2][4];
#pragma unroll
        for (int xi = 0; xi < 2; ++xi)
#pragma unroll
        for (int st = 0; st < 4; ++st) {
            u32x4 d;
#pragma unroll
            for (int p = 0; p < 4; ++p)
                d[p] = cvtpk_bf16(fr[xi][st][2 * p], fr[xi][st][2 * p + 1]);
            bx[xi][st] = __builtin_bit_cast(bf16x8, d);
        }

        // ---- prefetch next n's X + scalars (latency hides under tile loop) ----
        {
            const int n2 = nbase + 2 * ((it + 1 < nit) ? it + 1 : it);
            const float* xp = X + (size_t)n2 * NPX + 32 * cs + cl;
#pragma unroll
            for (int xi = 0; xi < 2; ++xi)
#pragma unroll
            for (int st = 0; st < 4; ++st)
#pragma unroll
            for (int j = 0; j < 8; ++j) {
                const int i = 16 * st + 8 * hb + j;
                fr[xi][st][j] = (i < KC) ? xp[128 * xi + (size_t)i * 256] : 0.0f;
            }
            const float* sp = S + (size_t)n2 * 384 + 32 * cs + cl;
            sraw0 = sp[0]; sraw1 = sp[128]; sraw2 = sp[256];
        }

        f32x16 accO0, accO1, fz;
#pragma unroll
        for (int r = 0; r < 16; ++r) { accO0[r] = 0.0f; accO1[r] = 0.0f; fz[r] = 0.0f; }

#pragma unroll 2
        for (int t = 0; t < NTILE; ++t) {
            // A-frags from LDS
            const unsigned short* twt = tw + t * TWTILE + cl * TWROW + hb * 8;
            const bf16x8 ta0 = *(const bf16x8*)(twt);
            const bf16x8 ta1 = *(const bf16x8*)(twt + 16);
            const bf16x8 ta2 = *(const bf16x8*)(twt + 32);
            const bf16x8 ta3 = *(const bf16x8*)(twt + 48);
            const unsigned short* fwt = fw + t * FWTILE + cl * FWROW + hb * 8;
            const bf16x8 fa00 = *(const bf16x8*)(fwt);
            const bf16x8 fa01 = *(const bf16x8*)(fwt + 16);
            const bf16x8 fa10 = *(const bf16x8*)(fwt + 32 * FWROW);
            const bf16x8 fa11 = *(const bf16x8*)(fwt + 32 * FWROW + 16);

            // GEMM1: 32pq x 32c, K=64 in 4 steps, both halves x1/x2
            f32x16 ac0 = fz, ac1 = fz;
            ac0 = __builtin_amdgcn_mfma_f32_32x32x16_bf16(ta0, bx[0][0], ac0, 0, 0, 0);
            ac1 = __builtin_amdgcn_mfma_f32_32x32x16_bf16(ta0, bx[1][0], ac1, 0, 0, 0);
            ac0 = __builtin_amdgcn_mfma_f32_32x32x16_bf16(ta1, bx[0][1], ac0, 0, 0, 0);
            ac1 = __builtin_amdgcn_mfma_f32_32x32x16_bf16(ta1, bx[1][1], ac1, 0, 0, 0);
            ac0 = __builtin_amdgcn_mfma_f32_32x32x16_bf16(ta2, bx[0][2], ac0, 0, 0, 0);
            ac1 = __builtin_amdgcn_mfma_f32_32x32x16_bf16(ta2, bx[1][2], ac1, 0, 0, 0);
            ac0 = __builtin_amdgcn_mfma_f32_32x32x16_bf16(ta3, bx[0][3], ac0, 0, 0, 0);
            ac1 = __builtin_amdgcn_mfma_f32_32x32x16_bf16(ta3, bx[1][3], ac1, 0, 0, 0);

            // gate + pack to bf16 pairs
            unsigned int q0 = cvtpk_bf16(ac0[0]  * ac1[0],  ac0[1]  * ac1[1]);
            unsigned int q1 = cvtpk_bf16(ac0[2]  * ac1[2],  ac0[3]  * ac1[3]);
            unsigned int q2 = cvtpk_bf16(ac0[4]  * ac1[4],  ac0[5]  * ac1[5]);
            unsigned int q3 = cvtpk_bf16(ac0[6]  * ac1[6],  ac0[7]  * ac1[7]);
            unsigned int q4 = cvtpk_bf16(ac0[8]  * ac1[8],  ac0[9]  * ac1[9]);
            unsigned int q5 = cvtpk_bf16(ac0[10] * ac1[10], ac0[11] * ac1[11]);
            unsigned int q6 = cvtpk_bf16(ac0[12] * ac1[12], ac0[13] * ac1[13]);
            unsigned int q7 = cvtpk_bf16(ac0[14] * ac1[14], ac0[15] * ac1[15]);

            // half-wave exchange: C-layout (4-row groups) -> B-frag layout (8-row groups)
            asm("v_permlane32_swap_b32 %0, %1" : "+v"(q0), "+v"(q2));
            asm("v_permlane32_swap_b32 %0, %1" : "+v"(q1), "+v"(q3));
            asm("v_permlane32_swap_b32 %0, %1" : "+v"(q4), "+v"(q6));
            asm("v_permlane32_swap_b32 %0, %1" : "+v"(q5), "+v"(q7));
            u32x4 b0v, b1v;
            b0v[0] = q0; b0v[1] = q1; b0v[2] = q2; b0v[3] = q3;
            b1v[0] = q4; b1v[1] = q5; b1v[2] = q6; b1v[3] = q7;
            const bf16x8 bg0 = __builtin_bit_cast(bf16x8, b0v);
            const bf16x8 bg1 = __builtin_bit_cast(bf16x8, b1v);

            // GEMM2: out-tiles k 0..31 / 32..63, two K=16 pq-steps
            accO0 = __builtin_amdgcn_mfma_f32_32x32x16_bf16(fa00, bg0, accO0, 0, 0, 0);
            accO1 = __builtin_amdgcn_mfma_f32_32x32x16_bf16(fa10, bg0, accO1, 0, 0, 0);
            accO0 = __builtin_amdgcn_mfma_f32_32x32x16_bf16(fa01, bg1, accO0, 0, 0, 0);
            accO1 = __builtin_amdgcn_mfma_f32_32x32x16_bf16(fa11, bg1, accO1, 0, 0, 0);
        }

        // ---- epilogue: gate, SwiGLU merge at k==0, store ----
        float* op = out + (size_t)n * OUTK + 32 * cs + cl;
#pragma unroll
        for (int r = 0; r < 16; ++r) {
            const int k0 = (r & 3) + 8 * (r >> 2) + 4 * hb;
            float v = sg * accO0[r];
            if (k0 == 0) v += osc;               // only r==0, hb==0
            op[(size_t)k0 * 128] = v;
            const int k1 = 32 + k0;
            if (k1 < KC) op[(size_t)k1 * 128] = sg * accO1[r];
        }
    }
}

extern "C" void kernel_launch(void* const* d_in, const int* in_sizes, int n_in,
                              void* d_out, int out_size, void* d_ws, size_t ws_size,
                              hipStream_t stream) {
    const float* inputs  = (const float*)d_in[0];
    const float* scalars = (const float*)d_in[1];
    const float* Tg      = (const float*)d_in[2];
    const float* Fg      = (const float*)d_in[3];
    float* outp          = (float*)d_out;

    unsigned short* W = (unsigned short*)d_ws;   // WTOT elems = 107008 B

    const int N = in_sizes[1] / 384;             // 4096
    hipLaunchKernelGGL(prep_kernel, dim3((WTOT + 255) / 256), dim3(256), 0, stream,
                       Tg, Fg, W);

    const int nit  = 4;                          // n-pairs per block
    const int grid = N / (2 * nit);              // 512 blocks, 8 n each
    hipLaunchKernelGGL(s2_fused, dim3(grid), dim3(512), 0, stream,
                       inputs, scalars, W, outp, nit);
}